// Round 6
// baseline (9984.351 us; speedup 1.0000x reference)
//
#include <hip/hip_runtime.h>
#include <hip/hip_fp16.h>

typedef _Float16 f16;
typedef f16 f16x8 __attribute__((ext_vector_type(8)));
typedef f16 f16x4 __attribute__((ext_vector_type(4)));
typedef float f32x4 __attribute__((ext_vector_type(4)));
typedef float f32x16 __attribute__((ext_vector_type(16)));

#define B_ 64
#define T_ 512
#define I_ 256
#define O_ 1024
#define M_ 8
#define IM_ 2048
#define NREC 64
#define NB 96
#define THREADS 256

// ws layout (bytes)
#define OFF_X16 4096ull
#define SZ_X16  ((unsigned long long)T_ * B_ * I_ * 2)   // 16 MB, [T][B][I] f16
#define OFF_XP3 (OFF_X16 + SZ_X16)                       // 3 x [B][IM] f16
#define SZ_XP3  (3ull * B_ * IM_ * 2)
#define OFF_H2  (OFF_XP3 + SZ_XP3)                       // 2 x [B][O] f16

// barrier uint indices (64B-separated lines)
#define MIDA  128
#define FLAGA 144
#define MIDB  288
#define FLAGB 304

#define WAITV(N) asm volatile("s_waitcnt vmcnt(" #N ")" ::: "memory")
#define LGKM0    asm volatile("s_waitcnt lgkmcnt(0)" ::: "memory")
#define SCHEDB   __builtin_amdgcn_sched_barrier(0)
#define BARRIER  __builtin_amdgcn_s_barrier()
// step-granular acquire: waitcnt + buffer_inv sc1 (invalidate stale L1/L2) —
// lets ALL state reads this step use plain cached loads that share L2 lines
// across the XCD's blocks instead of per-load sc1 fabric round-trips.
#define ACQ_FENCE __builtin_amdgcn_fence(__ATOMIC_ACQUIRE, "agent")

// 8 x 16B plain cached loads at 32B stride (x16 input / state after ACQ_FENCE)
#define ISSUE_AX(BUF, P) asm volatile( \
    "global_load_dwordx4 %0, %8, off\n\t" \
    "global_load_dwordx4 %1, %8, off offset:32\n\t" \
    "global_load_dwordx4 %2, %8, off offset:64\n\t" \
    "global_load_dwordx4 %3, %8, off offset:96\n\t" \
    "global_load_dwordx4 %4, %8, off offset:128\n\t" \
    "global_load_dwordx4 %5, %8, off offset:160\n\t" \
    "global_load_dwordx4 %6, %8, off offset:192\n\t" \
    "global_load_dwordx4 %7, %8, off offset:224" \
    : "=&v"(abuf[BUF][0]), "=&v"(abuf[BUF][1]), "=&v"(abuf[BUF][2]), "=&v"(abuf[BUF][3]), \
      "=&v"(abuf[BUF][4]), "=&v"(abuf[BUF][5]), "=&v"(abuf[BUF][6]), "=&v"(abuf[BUF][7]) \
    : "v"(P) : "memory")

#define ISSUE_AS(BUF, P) ISSUE_AX(BUF, P)

#define ISSUE_STG8(P0,P1,P2,P3,P4,P5,P6,P7) asm volatile( \
    "global_load_dwordx4 %0, %8, off\n\t" \
    "global_load_dwordx4 %1, %9, off\n\t" \
    "global_load_dwordx4 %2, %10, off\n\t" \
    "global_load_dwordx4 %3, %11, off\n\t" \
    "global_load_dwordx4 %4, %12, off\n\t" \
    "global_load_dwordx4 %5, %13, off\n\t" \
    "global_load_dwordx4 %6, %14, off\n\t" \
    "global_load_dwordx4 %7, %15, off" \
    : "=&v"(sreg[0]), "=&v"(sreg[1]), "=&v"(sreg[2]), "=&v"(sreg[3]), \
      "=&v"(sreg[4]), "=&v"(sreg[5]), "=&v"(sreg[6]), "=&v"(sreg[7]) \
    : "v"(P0), "v"(P1), "v"(P2), "v"(P3), "v"(P4), "v"(P5), "v"(P6), "v"(P7) \
    : "memory")

// prologue issue of chunk c0+J into buffer J
#define GM_PRO(J) do { \
    const int c_ = c0 + (J); \
    if (c_ < 2) { const char* p_ = xrow + c_ * 256;  ISSUE_AX(J, p_); } \
    else        { const char* p_ = sprow + c_ * 256; ISSUE_AS(J, p_); } \
} while (0)

// REC chunk iteration, 4 buffers: counted wait, compute, then reissue 4 ahead
#define GM_ITR(I, WN, DOISS) do { \
    WAITV(WN); \
    _Pragma("unroll") \
    for (int kb = 0; kb < 8; ++kb) { \
        f16x8 bf = *(const f16x8*)(smem + addrB[kb] + (I) * 256); \
        if (kb & 1) acc1 = __builtin_amdgcn_mfma_f32_32x32x16_f16(abuf[(I) & 3][kb], bf, acc1, 0, 0, 0); \
        else        acc0 = __builtin_amdgcn_mfma_f32_32x32x16_f16(abuf[(I) & 3][kb], bf, acc0, 0, 0, 0); \
    } \
    SCHEDB; \
    if (DOISS) { const char* p_ = sprow + (c0 + (I) + 4) * 256; ISSUE_AS(((I) & 3), p_); } \
} while (0)

// ACT chunk iteration, 3 buffers
#define GM_ITA(I, WN, DOISS) do { \
    WAITV(WN); \
    _Pragma("unroll") \
    for (int kb = 0; kb < 8; ++kb) { \
        f16x8 bf = *(const f16x8*)(smem + addrB[kb] + (I) * 256); \
        if (kb & 1) acc1 = __builtin_amdgcn_mfma_f32_32x32x16_f16(abuf[(I) % 3][kb], bf, acc1, 0, 0, 0); \
        else        acc0 = __builtin_amdgcn_mfma_f32_32x32x16_f16(abuf[(I) % 3][kb], bf, acc0, 0, 0, 0); \
    } \
    SCHEDB; \
    if (DOISS) { const char* p_ = sprow + (c0 + (I) + 3) * 256; ISSUE_AS(((I) % 3), p_); } \
} while (0)

__device__ __forceinline__ void st_coh_h(f16* p, float vf) {
    union { f16 h; short s; } u; u.h = (f16)vf;
    asm volatile("global_store_short %0, %1, off sc0 sc1" :: "v"(p), "v"((int)u.s) : "memory");
}

__device__ __forceinline__ float fast_tanh(float x) {
    float e = __expf(2.f * x);
    return 1.f - 2.f / (e + 1.f);
}

__device__ __forceinline__ unsigned ld_rlx(unsigned* p) {
    return __hip_atomic_load(p, __ATOMIC_RELAXED, __HIP_MEMORY_SCOPE_AGENT);
}

__device__ __forceinline__ void arriveA(unsigned* bar, int blk) {
    unsigned old = __hip_atomic_fetch_add(&bar[(blk & 7) * 16], 1u, __ATOMIC_RELAXED, __HIP_MEMORY_SCOPE_AGENT);
    if ((old & 7u) == 7u) {
        unsigned r = __hip_atomic_fetch_add(&bar[MIDA], 1u, __ATOMIC_RELAXED, __HIP_MEMORY_SCOPE_AGENT);
        if ((r & 7u) == 7u)
            __hip_atomic_fetch_add(&bar[FLAGA], 1u, __ATOMIC_RELAXED, __HIP_MEMORY_SCOPE_AGENT);
    }
}
__device__ __forceinline__ void arriveB(unsigned* bar, int a) {
    unsigned old = __hip_atomic_fetch_add(&bar[160 + (a & 7) * 16], 1u, __ATOMIC_RELAXED, __HIP_MEMORY_SCOPE_AGENT);
    if ((old & 3u) == 3u) {
        unsigned r = __hip_atomic_fetch_add(&bar[MIDB], 1u, __ATOMIC_RELAXED, __HIP_MEMORY_SCOPE_AGENT);
        if ((r & 7u) == 7u)
            __hip_atomic_fetch_add(&bar[FLAGB], 1u, __ATOMIC_RELAXED, __HIP_MEMORY_SCOPE_AGENT);
    }
}

// init: zero barriers+state, convert x [B,T,I] f32 -> x16 [T,B,I] f16
__global__ void init_kernel(const float* __restrict__ x, char* __restrict__ ws) {
    const int gid = blockIdx.x * THREADS + threadIdx.x;
    if (blockIdx.x == 0) {
        for (int i = threadIdx.x; i < 512; i += THREADS) ((unsigned*)ws)[i] = 0u;
    }
    f16* x16 = (f16*)(ws + OFF_X16);
    const int NQ = T_ * B_ * (I_ / 4);
    for (int q = gid; q < NQ; q += 256 * THREADS) {
        int t = q >> 12;
        int rem = q & 4095;
        int b = rem >> 6;
        int k4 = rem & 63;
        f32x4 v = *(const f32x4*)(x + ((size_t)b * T_ + t) * I_ + k4 * 4);
        f16x4 h;
        h[0] = (f16)v[0]; h[1] = (f16)v[1]; h[2] = (f16)v[2]; h[3] = (f16)v[3];
        *(f16x4*)(x16 + ((size_t)t * B_ + b) * I_ + k4 * 4) = h;
    }
    f16x8 z = {0, 0, 0, 0, 0, 0, 0, 0};
    f16* xp0 = (f16*)(ws + OFF_XP3);
    for (int e = gid * 8; e < B_ * IM_; e += 256 * THREADS * 8) *(f16x8*)(xp0 + e) = z;
    f16* h0 = (f16*)(ws + OFF_H2);
    for (int e = gid * 8; e < B_ * O_; e += 256 * THREADS * 8) *(f16x8*)(h0 + e) = z;
}

__global__ __launch_bounds__(THREADS, 1) void cwrnn_kernel(
    const float* __restrict__ x, const float* __restrict__ W_in, const float* __restrict__ b_in,
    const float* __restrict__ W_h, const float* __restrict__ W_ir, const float* __restrict__ b_ir,
    const float* __restrict__ W_hr, const float* __restrict__ periods, const float* __restrict__ shifts,
    float* __restrict__ out, char* __restrict__ ws)
{
    __shared__ __align__(16) char smem[157696];
    // REC: W[32][2304] swz @0 (147456) | accx @147456 (10240)
    // ACT: W[32][1280] swz @0 (81920) | xp_raw @81920 (32768) | accx @114688 (10240)
    //      lse @124928 | part @125952 | gate @126976

    unsigned* bar = (unsigned*)ws;
    const int blk = blockIdx.x, tid = threadIdx.x;
    const int lane = tid & 63, w = tid >> 6;
    const int col = lane & 31, g = lane >> 5;
    const int pair = w >> 1;
    const int arow = ((w & 1) << 5) + col;

    float* ys = out;
    float* hfin = out + (size_t)B_ * T_ * O_;
    float* ps = hfin + (size_t)B_ * O_;

    if (blk < NREC) {
        // ================= x_pred recurrence blocks: cols j0..j0+31 of acts_rec =================
        const int j0 = blk * 32;
        {   // stage W2 = [W_ir | W_hr] rows j0..j0+31 into swizzled LDS (once)
            const int j = tid >> 3;
            const float* ra = W_ir + (size_t)(j0 + j) * I_;
            const float* rb = W_hr + (size_t)(j0 + j) * IM_ - 256;
            for (int u = (tid & 7); u < 288; u += 8) {
                int k0 = u * 8;
                const float* s = (k0 < 256) ? (ra + k0) : (rb + k0);
                f32x4 lo = *(const f32x4*)s;
                f32x4 hi = *(const f32x4*)(s + 4);
                f16x8 v;
                #pragma unroll
                for (int e = 0; e < 4; ++e) { v[e] = (f16)lo[e]; v[e + 4] = (f16)hi[e]; }
                *(f16x8*)(smem + j * 4608 + ((u ^ (j & 15)) << 4)) = v;
            }
        }
        const float bir = b_ir[j0 + col];
        LGKM0; BARRIER;

        int addrB[8];
        const int c0 = pair * 9;
        #pragma unroll
        for (int kb = 0; kb < 8; ++kb)
            addrB[kb] = col * 4608 + ((((kb << 1) + g) ^ (col & 15)) << 4) + c0 * 256;

        const char* xrow0 = (const char*)(ws + OFF_X16) + (size_t)arow * 512 + g * 16;
        f16* const xpB = (f16*)(ws + OFF_XP3);

        for (int t = 0; t < T_ - 1; ++t) {
            if (tid == 0) {
                while (1) {
                    int fa = (int)ld_rlx(&bar[FLAGA]);
                    int fb = (int)ld_rlx(&bar[FLAGB]);
                    if (fa >= t && fb >= t - 1) break;
                    __builtin_amdgcn_s_sleep(1);
                }
            }
            BARRIER;
            ACQ_FENCE;   // invalidate stale L1/L2 once; all state loads below are plain/cached
            const int bi = t % 3;
            int bn = bi + 1; if (bn == 3) bn = 0;
            const f16* xpcur = xpB + (size_t)bi * B_ * IM_;
            f16* xpnxt = xpB + (size_t)bn * B_ * IM_;
            const char* sprow = (const char*)xpcur + (size_t)arow * 4096 + g * 16 - 512;
            const char* xrow = xrow0 + (size_t)t * 32768;

            f16x8 abuf[4][8];
            f32x16 acc0, acc1;
            #pragma unroll
            for (int r = 0; r < 16; ++r) { acc0[r] = 0.f; acc1[r] = 0.f; }

            GM_PRO(0); GM_PRO(1); GM_PRO(2); GM_PRO(3);
            GM_ITR(0, 24, 1); GM_ITR(1, 24, 1); GM_ITR(2, 24, 1); GM_ITR(3, 24, 1);
            GM_ITR(4, 24, 1); GM_ITR(5, 24, 0); GM_ITR(6, 16, 0); GM_ITR(7, 8, 0); GM_ITR(8, 0, 0);

            f32x16 accS;
            #pragma unroll
            for (int r = 0; r < 16; ++r) accS[r] = acc0[r] + acc1[r];
            if (w >= 2) {
                char* axp = smem + 147456 + (w - 2) * 5120 + lane * 80;
                #pragma unroll
                for (int q = 0; q < 4; ++q) {
                    f32x4 v = { accS[q * 4 + 0], accS[q * 4 + 1], accS[q * 4 + 2], accS[q * 4 + 3] };
                    *(f32x4*)(axp + q * 16) = v;
                }
            }
            LGKM0; BARRIER;
            if (w < 2) {
                const char* axp = smem + 147456 + w * 5120 + lane * 80;
                #pragma unroll
                for (int q = 0; q < 4; ++q) {
                    f32x4 v = *(const f32x4*)(axp + q * 16);
                    accS[q * 4 + 0] += v[0]; accS[q * 4 + 1] += v[1];
                    accS[q * 4 + 2] += v[2]; accS[q * 4 + 3] += v[3];
                }
                #pragma unroll
                for (int r = 0; r < 16; ++r) {
                    int row = (r & 3) + ((r >> 2) << 3) + (g << 2) + (w << 5);
                    st_coh_h(xpnxt + (size_t)row * IM_ + j0 + col, fast_tanh(accS[r] + bir));
                }
            }
            WAITV(0);
            BARRIER;
            if (tid == 0) arriveA(bar, blk);
        }
    } else {
        // ================= acts/gate/output blocks: cols o0..o0+31 =================
        const int a = blk - NREC;
        const int m = a >> 2;
        const int o0 = a * 32;
        {   // stage W1 = [W_in | W_h] rows o0..o0+31
            const int j = tid >> 3;
            const float* ra = W_in + (size_t)(o0 + j) * I_;
            const float* rb = W_h + (size_t)(o0 + j) * O_ - 256;
            for (int u = (tid & 7); u < 160; u += 8) {
                int k0 = u * 8;
                const float* s = (k0 < 256) ? (ra + k0) : (rb + k0);
                f32x4 lo = *(const f32x4*)s;
                f32x4 hi = *(const f32x4*)(s + 4);
                f16x8 v;
                #pragma unroll
                for (int e = 0; e < 4; ++e) { v[e] = (f16)lo[e]; v[e + 4] = (f16)hi[e]; }
                *(f16x8*)(smem + j * 2560 + ((u ^ (j & 15)) << 4)) = v;
            }
        }
        const float bin = b_in[o0 + col];
        const float per = periods[m], shf = shifts[m];
        LGKM0; BARRIER;

        int addrB[8];
        const int c0 = pair * 5;
        #pragma unroll
        for (int kb = 0; kb < 8; ++kb)
            addrB[kb] = col * 2560 + ((((kb << 1) + g) ^ (col & 15)) << 4) + c0 * 256;

        char* xp_raw = smem + 81920;
        float* lse_lds = (float*)(smem + 124928);
        float* part_lds = (float*)(smem + 125952);
        float* gate_lds = (float*)(smem + 126976);

        const char* xrow0 = (const char*)(ws + OFF_X16) + (size_t)arow * 512 + g * 16;
        const f16* xpB = (const f16*)(ws + OFF_XP3);
        f16* h2 = (f16*)(ws + OFF_H2);
        const int t5 = tid >> 5, cg = tid & 31;
        float hreg[16];
        #pragma unroll
        for (int r = 0; r < 16; ++r) hreg[r] = 0.f;

        for (int t = 0; t < T_; ++t) {
            if (tid == 0) {
                while (1) {
                    int fa = (int)ld_rlx(&bar[FLAGA]);
                    int fb = (int)ld_rlx(&bar[FLAGB]);
                    if (fa >= t && fb >= t) break;
                    __builtin_amdgcn_s_sleep(1);
                }
            }
            BARRIER;
            ACQ_FENCE;   // invalidate stale L1/L2 once; all state loads below are plain/cached
            const int bi = t % 3;
            const f16* xpcur = xpB + (size_t)bi * B_ * IM_;
            const f16* hcur = h2 + (size_t)(t & 1) * B_ * O_;
            f16* hnxt = h2 + (size_t)((t + 1) & 1) * B_ * O_;

            // issue softmax-slice staging loads first (latency hidden under GEMM)
            f16x8 sreg[8];
            {
                const char* sb = (const char*)xpcur + (size_t)m * 512 + (size_t)cg * 16 + (size_t)t5 * 4096;
                ISSUE_STG8(sb, sb + 32768, sb + 2 * 32768, sb + 3 * 32768,
                           sb + 4 * 32768, sb + 5 * 32768, sb + 6 * 32768, sb + 7 * 32768);
            }

            const char* sprow = (const char*)hcur + (size_t)arow * 2048 + g * 16 - 512;
            const char* xrow = xrow0 + (size_t)t * 32768;
            f16x8 abuf[3][8];
            f32x16 acc0, acc1;
            #pragma unroll
            for (int r = 0; r < 16; ++r) { acc0[r] = 0.f; acc1[r] = 0.f; }

            GM_PRO(0); GM_PRO(1); GM_PRO(2);
            // it0: wait sreg + c0; park sreg; compute c0; issue c3
            WAITV(16);
            {
                const int gsw = (cg ^ t5) << 4;
                #pragma unroll
                for (int k = 0; k < 8; ++k)
                    *(f16x8*)(xp_raw + (size_t)(t5 + (k << 3)) * 512 + gsw) = sreg[k];
            }
            #pragma unroll
            for (int kb = 0; kb < 8; ++kb) {
                f16x8 bf = *(const f16x8*)(smem + addrB[kb]);
                if (kb & 1) acc1 = __builtin_amdgcn_mfma_f32_32x32x16_f16(abuf[0][kb], bf, acc1, 0, 0, 0);
                else        acc0 = __builtin_amdgcn_mfma_f32_32x32x16_f16(abuf[0][kb], bf, acc0, 0, 0, 0);
            }
            SCHEDB;
            { const char* p_ = sprow + (c0 + 3) * 256; ISSUE_AS(0, p_); }
            GM_ITA(1, 16, 1); GM_ITA(2, 16, 0); GM_ITA(3, 8, 0); GM_ITA(4, 0, 0);

            f32x16 accS;
            #pragma unroll
            for (int r = 0; r < 16; ++r) accS[r] = acc0[r] + acc1[r];
            if (w >= 2) {
                char* axp = smem + 114688 + (w - 2) * 5120 + lane * 80;
                #pragma unroll
                for (int q = 0; q < 4; ++q) {
                    f32x4 v = { accS[q * 4 + 0], accS[q * 4 + 1], accS[q * 4 + 2], accS[q * 4 + 3] };
                    *(f32x4*)(axp + q * 16) = v;
                }
            }
            LGKM0; BARRIER;
            {   // lse over batch axis, feature i = tid
                int i = tid;
                int gq = i >> 3, r2 = (i & 7) * 2;
                float mx = -1e30f;
                #pragma unroll 8
                for (int b = 0; b < B_; ++b)
                    mx = fmaxf(mx, (float)*(const f16*)(xp_raw + b * 512 + ((gq ^ (b & 7)) << 4) + r2));
                float s = 0.f;
                #pragma unroll 8
                for (int b = 0; b < B_; ++b)
                    s += __expf((float)*(const f16*)(xp_raw + b * 512 + ((gq ^ (b & 7)) << 4) + r2) - mx);
                lse_lds[i] = mx + __logf(s);
            }
            LGKM0; BARRIER;
            {   // mean surprisal partial dots: thread = (b, quarter)
                int b = tid >> 2, q = tid & 3;
                const float* xr = x + ((size_t)b * T_ + t) * I_ + q * 64;
                float s = 0.f;
                #pragma unroll
                for (int k = 0; k < 8; ++k) {
                    f16x8 xp8 = *(const f16x8*)(xp_raw + (size_t)b * 512 + ((((q << 3) + k) ^ (b & 7)) << 4));
                    f32x4 xa = *(const f32x4*)(xr + k * 8);
                    f32x4 xb2 = *(const f32x4*)(xr + k * 8 + 4);
                    #pragma unroll
                    for (int jj = 0; jj < 4; ++jj)
                        s += ((float)xp8[jj] - lse_lds[(q << 6) + (k << 3) + jj]) * xa[jj];
                    #pragma unroll
                    for (int jj = 0; jj < 4; ++jj)
                        s += ((float)xp8[jj + 4] - lse_lds[(q << 6) + (k << 3) + 4 + jj]) * xb2[jj];
                }
                part_lds[tid] = s;
            }
            LGKM0; BARRIER;
            if (tid < B_) {
                float s = part_lds[tid * 4] + part_lds[tid * 4 + 1] + part_lds[tid * 4 + 2] + part_lds[tid * 4 + 3];
                float mp = (s * (1.f / 256.f)) * per;
                gate_lds[tid] = 0.5f * (sinf((float)t * mp + shf) + 1.f);
                if ((a & 3) == 0) ps[((size_t)tid * T_ + t) * M_ + m] = mp;
            }
            LGKM0; BARRIER;
            if (w < 2) {
                const char* axp = smem + 114688 + w * 5120 + lane * 80;
                #pragma unroll
                for (int q = 0; q < 4; ++q) {
                    f32x4 v = *(const f32x4*)(axp + q * 16);
                    accS[q * 4 + 0] += v[0]; accS[q * 4 + 1] += v[1];
                    accS[q * 4 + 2] += v[2]; accS[q * 4 + 3] += v[3];
                }
                #pragma unroll
                for (int r = 0; r < 16; ++r) {
                    int row = (r & 3) + ((r >> 2) << 3) + (g << 2) + (w << 5);
                    float gt = gate_lds[row];
                    float av = fast_tanh(accS[r] + bin);
                    float y = (1.f - gt) * av + gt * hreg[r];
                    hreg[r] = y;
                    ys[((size_t)row * T_ + t) * O_ + o0 + col] = y;
                    st_coh_h(hnxt + (size_t)row * O_ + o0 + col, y);
                    if (t == T_ - 1) hfin[(size_t)row * O_ + o0 + col] = y;
                }
            }
            WAITV(0);
            BARRIER;
            if (tid == 0) arriveB(bar, a);
        }
    }
}

extern "C" void kernel_launch(void* const* d_in, const int* in_sizes, int n_in,
                              void* d_out, int out_size, void* d_ws, size_t ws_size,
                              hipStream_t stream) {
    const float* x    = (const float*)d_in[0];
    const float* W_in = (const float*)d_in[1];
    const float* b_in = (const float*)d_in[2];
    const float* W_h  = (const float*)d_in[3];
    const float* W_ir = (const float*)d_in[4];
    const float* b_ir = (const float*)d_in[5];
    const float* W_hr = (const float*)d_in[6];
    const float* per  = (const float*)d_in[7];
    const float* shf  = (const float*)d_in[8];

    hipLaunchKernelGGL(init_kernel, dim3(256), dim3(THREADS), 0, stream,
                       x, (char*)d_ws);
    hipLaunchKernelGGL(cwrnn_kernel, dim3(NB), dim3(THREADS), 0, stream,
                       x, W_in, b_in, W_h, W_ir, b_ir, W_hr, per, shf,
                       (float*)d_out, (char*)d_ws);
}

// Round 7
// 6466.602 us; speedup vs baseline: 1.5440x; 1.5440x over previous
//
#include <hip/hip_runtime.h>
#include <hip/hip_fp16.h>

typedef _Float16 f16;
typedef f16 f16x8 __attribute__((ext_vector_type(8)));
typedef f16 f16x4 __attribute__((ext_vector_type(4)));
typedef float f32x4 __attribute__((ext_vector_type(4)));
typedef float f32x16 __attribute__((ext_vector_type(16)));

#define B_ 64
#define T_ 512
#define I_ 256
#define O_ 1024
#define M_ 8
#define IM_ 2048
#define NREC 64
#define NB 96
#define THREADS 256

// ws layout (bytes)
#define OFF_X16 4096ull
#define SZ_X16  ((unsigned long long)T_ * B_ * I_ * 2)   // 16 MB, [T][B][I] f16
#define OFF_XP3 (OFF_X16 + SZ_X16)                       // 3 x [B][IM] f16
#define SZ_XP3  (3ull * B_ * IM_ * 2)
#define OFF_H2  (OFF_XP3 + SZ_XP3)                       // 2 x [B][O] f16

// combined barrier: 8 leaves (12 arrivals each) -> central (8) -> 8 replicated flags
#define BAR_LEAF(i) ((i) * 16)
#define BAR_CENT    128
#define BAR_REPL(i) (192 + (i) * 16)

#define WAITV(N) asm volatile("s_waitcnt vmcnt(" #N ")" ::: "memory")
#define LGKM0    asm volatile("s_waitcnt lgkmcnt(0)" ::: "memory")
#define SCHEDB   __builtin_amdgcn_sched_barrier(0)
#define BARRIER  __builtin_amdgcn_s_barrier()

// 8 x 16B plain cached loads at 32B stride (read-only x16 input)
#define ISSUE_AX(BUF, P) asm volatile( \
    "global_load_dwordx4 %0, %8, off\n\t" \
    "global_load_dwordx4 %1, %8, off offset:32\n\t" \
    "global_load_dwordx4 %2, %8, off offset:64\n\t" \
    "global_load_dwordx4 %3, %8, off offset:96\n\t" \
    "global_load_dwordx4 %4, %8, off offset:128\n\t" \
    "global_load_dwordx4 %5, %8, off offset:160\n\t" \
    "global_load_dwordx4 %6, %8, off offset:192\n\t" \
    "global_load_dwordx4 %7, %8, off offset:224" \
    : "=&v"(abuf[BUF][0]), "=&v"(abuf[BUF][1]), "=&v"(abuf[BUF][2]), "=&v"(abuf[BUF][3]), \
      "=&v"(abuf[BUF][4]), "=&v"(abuf[BUF][5]), "=&v"(abuf[BUF][6]), "=&v"(abuf[BUF][7]) \
    : "v"(P) : "memory")

// 8 x 16B coherent (device-scope) loads at 32B stride (cross-XCD state)
#define ISSUE_AS(BUF, P) asm volatile( \
    "global_load_dwordx4 %0, %8, off sc0 sc1\n\t" \
    "global_load_dwordx4 %1, %8, off offset:32 sc0 sc1\n\t" \
    "global_load_dwordx4 %2, %8, off offset:64 sc0 sc1\n\t" \
    "global_load_dwordx4 %3, %8, off offset:96 sc0 sc1\n\t" \
    "global_load_dwordx4 %4, %8, off offset:128 sc0 sc1\n\t" \
    "global_load_dwordx4 %5, %8, off offset:160 sc0 sc1\n\t" \
    "global_load_dwordx4 %6, %8, off offset:192 sc0 sc1\n\t" \
    "global_load_dwordx4 %7, %8, off offset:224 sc0 sc1" \
    : "=&v"(abuf[BUF][0]), "=&v"(abuf[BUF][1]), "=&v"(abuf[BUF][2]), "=&v"(abuf[BUF][3]), \
      "=&v"(abuf[BUF][4]), "=&v"(abuf[BUF][5]), "=&v"(abuf[BUF][6]), "=&v"(abuf[BUF][7]) \
    : "v"(P) : "memory")

#define ISSUE_STG8(P0,P1,P2,P3,P4,P5,P6,P7) asm volatile( \
    "global_load_dwordx4 %0, %8, off sc0 sc1\n\t" \
    "global_load_dwordx4 %1, %9, off sc0 sc1\n\t" \
    "global_load_dwordx4 %2, %10, off sc0 sc1\n\t" \
    "global_load_dwordx4 %3, %11, off sc0 sc1\n\t" \
    "global_load_dwordx4 %4, %12, off sc0 sc1\n\t" \
    "global_load_dwordx4 %5, %13, off sc0 sc1\n\t" \
    "global_load_dwordx4 %6, %14, off sc0 sc1\n\t" \
    "global_load_dwordx4 %7, %15, off sc0 sc1" \
    : "=&v"(sreg[0]), "=&v"(sreg[1]), "=&v"(sreg[2]), "=&v"(sreg[3]), \
      "=&v"(sreg[4]), "=&v"(sreg[5]), "=&v"(sreg[6]), "=&v"(sreg[7]) \
    : "v"(P0), "v"(P1), "v"(P2), "v"(P3), "v"(P4), "v"(P5), "v"(P6), "v"(P7) \
    : "memory")

// prologue issue of chunk c0+J into buffer J
#define GM_PRO(J) do { \
    const int c_ = c0 + (J); \
    if (c_ < 2) { const char* p_ = xrow + c_ * 256;  ISSUE_AX(J, p_); } \
    else        { const char* p_ = sprow + c_ * 256; ISSUE_AS(J, p_); } \
} while (0)

// REC chunk iteration, 4 buffers: counted wait, compute, then reissue 4 ahead
#define GM_ITR(I, WN, DOISS) do { \
    WAITV(WN); \
    _Pragma("unroll") \
    for (int kb = 0; kb < 8; ++kb) { \
        f16x8 bf = *(const f16x8*)(smem + addrB[kb] + (I) * 256); \
        if (kb & 1) acc1 = __builtin_amdgcn_mfma_f32_32x32x16_f16(abuf[(I) & 3][kb], bf, acc1, 0, 0, 0); \
        else        acc0 = __builtin_amdgcn_mfma_f32_32x32x16_f16(abuf[(I) & 3][kb], bf, acc0, 0, 0, 0); \
    } \
    SCHEDB; \
    if (DOISS) { const char* p_ = sprow + (c0 + (I) + 4) * 256; ISSUE_AS(((I) & 3), p_); } \
} while (0)

// ACT chunk iteration, 3 buffers
#define GM_ITA(I, WN, DOISS) do { \
    WAITV(WN); \
    _Pragma("unroll") \
    for (int kb = 0; kb < 8; ++kb) { \
        f16x8 bf = *(const f16x8*)(smem + addrB[kb] + (I) * 256); \
        if (kb & 1) acc1 = __builtin_amdgcn_mfma_f32_32x32x16_f16(abuf[(I) % 3][kb], bf, acc1, 0, 0, 0); \
        else        acc0 = __builtin_amdgcn_mfma_f32_32x32x16_f16(abuf[(I) % 3][kb], bf, acc0, 0, 0, 0); \
    } \
    SCHEDB; \
    if (DOISS) { const char* p_ = sprow + (c0 + (I) + 3) * 256; ISSUE_AS(((I) % 3), p_); } \
} while (0)

__device__ __forceinline__ void st_coh_h(f16* p, float vf) {
    union { f16 h; short s; } u; u.h = (f16)vf;
    asm volatile("global_store_short %0, %1, off sc0 sc1" :: "v"(p), "v"((int)u.s) : "memory");
}

__device__ __forceinline__ float fast_tanh(float x) {
    float e = __expf(2.f * x);
    return 1.f - 2.f / (e + 1.f);
}

__device__ __forceinline__ unsigned ld_rlx(unsigned* p) {
    return __hip_atomic_load(p, __ATOMIC_RELAXED, __HIP_MEMORY_SCOPE_AGENT);
}

// combined grid barrier arrival: 96 arrivals/step -> leaf(12) -> central(8) -> 8 replica flags
__device__ __forceinline__ void arrive_all(unsigned* bar, int blk, int t) {
    unsigned old = __hip_atomic_fetch_add(&bar[BAR_LEAF(blk & 7)], 1u, __ATOMIC_RELAXED, __HIP_MEMORY_SCOPE_AGENT);
    if (old % 12u == 11u) {
        unsigned r = __hip_atomic_fetch_add(&bar[BAR_CENT], 1u, __ATOMIC_RELAXED, __HIP_MEMORY_SCOPE_AGENT);
        if ((r & 7u) == 7u) {
            unsigned v = (unsigned)(t + 1);
            #pragma unroll
            for (int i = 0; i < 8; ++i) {
                unsigned* rp = &bar[BAR_REPL(i)];
                asm volatile("global_store_dword %0, %1, off sc0 sc1" :: "v"(rp), "v"(v) : "memory");
            }
        }
    }
}

// init: zero barriers+state, convert x [B,T,I] f32 -> x16 [T,B,I] f16
__global__ void init_kernel(const float* __restrict__ x, char* __restrict__ ws) {
    const int gid = blockIdx.x * THREADS + threadIdx.x;
    if (blockIdx.x == 0) {
        for (int i = threadIdx.x; i < 512; i += THREADS) ((unsigned*)ws)[i] = 0u;
    }
    f16* x16 = (f16*)(ws + OFF_X16);
    const int NQ = T_ * B_ * (I_ / 4);
    for (int q = gid; q < NQ; q += 256 * THREADS) {
        int t = q >> 12;
        int rem = q & 4095;
        int b = rem >> 6;
        int k4 = rem & 63;
        f32x4 v = *(const f32x4*)(x + ((size_t)b * T_ + t) * I_ + k4 * 4);
        f16x4 h;
        h[0] = (f16)v[0]; h[1] = (f16)v[1]; h[2] = (f16)v[2]; h[3] = (f16)v[3];
        *(f16x4*)(x16 + ((size_t)t * B_ + b) * I_ + k4 * 4) = h;
    }
    f16x8 z = {0, 0, 0, 0, 0, 0, 0, 0};
    f16* xp0 = (f16*)(ws + OFF_XP3);
    for (int e = gid * 8; e < B_ * IM_; e += 256 * THREADS * 8) *(f16x8*)(xp0 + e) = z;
    f16* h0 = (f16*)(ws + OFF_H2);
    for (int e = gid * 8; e < B_ * O_; e += 256 * THREADS * 8) *(f16x8*)(h0 + e) = z;
}

__global__ __launch_bounds__(THREADS, 1) void cwrnn_kernel(
    const float* __restrict__ x, const float* __restrict__ W_in, const float* __restrict__ b_in,
    const float* __restrict__ W_h, const float* __restrict__ W_ir, const float* __restrict__ b_ir,
    const float* __restrict__ W_hr, const float* __restrict__ periods, const float* __restrict__ shifts,
    float* __restrict__ out, char* __restrict__ ws)
{
    __shared__ __align__(16) char smem[157696];
    // REC: W[32][2304] swz @0 (147456) | accx @147456 (10240)
    // ACT: W[32][1280] swz @0 (81920) | xp_raw @81920 (32768) | accx @114688 (10240)
    //      lse @124928 | part @125952 | gate @126976

    unsigned* bar = (unsigned*)ws;
    const int blk = blockIdx.x, tid = threadIdx.x;
    const int lane = tid & 63, w = tid >> 6;
    const int col = lane & 31, g = lane >> 5;
    const int pair = w >> 1;
    const int arow = ((w & 1) << 5) + col;

    float* ys = out;
    float* hfin = out + (size_t)B_ * T_ * O_;
    float* ps = hfin + (size_t)B_ * O_;

    unsigned* myrepl = &bar[BAR_REPL(blk & 7)];

    if (blk < NREC) {
        // ================= x_pred recurrence blocks: cols j0..j0+31 of acts_rec =================
        const int j0 = blk * 32;
        {   // stage W2 = [W_ir | W_hr] rows j0..j0+31 into swizzled LDS (once)
            const int j = tid >> 3;
            const float* ra = W_ir + (size_t)(j0 + j) * I_;
            const float* rb = W_hr + (size_t)(j0 + j) * IM_ - 256;
            for (int u = (tid & 7); u < 288; u += 8) {
                int k0 = u * 8;
                const float* s = (k0 < 256) ? (ra + k0) : (rb + k0);
                f32x4 lo = *(const f32x4*)s;
                f32x4 hi = *(const f32x4*)(s + 4);
                f16x8 v;
                #pragma unroll
                for (int e = 0; e < 4; ++e) { v[e] = (f16)lo[e]; v[e + 4] = (f16)hi[e]; }
                *(f16x8*)(smem + j * 4608 + ((u ^ (j & 15)) << 4)) = v;
            }
        }
        const float bir = b_ir[j0 + col];
        LGKM0; BARRIER;

        int addrB[8];
        const int c0 = pair * 9;
        #pragma unroll
        for (int kb = 0; kb < 8; ++kb)
            addrB[kb] = col * 4608 + ((((kb << 1) + g) ^ (col & 15)) << 4) + c0 * 256;

        const char* xrow0 = (const char*)(ws + OFF_X16) + (size_t)arow * 512 + g * 16;
        f16* const xpB = (f16*)(ws + OFF_XP3);

        for (int t = 0; t < T_ - 1; ++t) {
            if (tid == 0) {
                while ((int)ld_rlx(myrepl) < t) __builtin_amdgcn_s_sleep(2);
            }
            BARRIER;
            const int bi = t % 3;
            int bn = bi + 1; if (bn == 3) bn = 0;
            const f16* xpcur = xpB + (size_t)bi * B_ * IM_;
            f16* xpnxt = xpB + (size_t)bn * B_ * IM_;
            const char* sprow = (const char*)xpcur + (size_t)arow * 4096 + g * 16 - 512;
            const char* xrow = xrow0 + (size_t)t * 32768;

            f16x8 abuf[4][8];
            f32x16 acc0, acc1;
            #pragma unroll
            for (int r = 0; r < 16; ++r) { acc0[r] = 0.f; acc1[r] = 0.f; }

            GM_PRO(0); GM_PRO(1); GM_PRO(2); GM_PRO(3);
            GM_ITR(0, 24, 1); GM_ITR(1, 24, 1); GM_ITR(2, 24, 1); GM_ITR(3, 24, 1);
            GM_ITR(4, 24, 1); GM_ITR(5, 24, 0); GM_ITR(6, 16, 0); GM_ITR(7, 8, 0); GM_ITR(8, 0, 0);

            f32x16 accS;
            #pragma unroll
            for (int r = 0; r < 16; ++r) accS[r] = acc0[r] + acc1[r];
            if (w >= 2) {
                char* axp = smem + 147456 + (w - 2) * 5120 + lane * 80;
                #pragma unroll
                for (int q = 0; q < 4; ++q) {
                    f32x4 v = { accS[q * 4 + 0], accS[q * 4 + 1], accS[q * 4 + 2], accS[q * 4 + 3] };
                    *(f32x4*)(axp + q * 16) = v;
                }
            }
            LGKM0; BARRIER;
            if (w < 2) {
                const char* axp = smem + 147456 + w * 5120 + lane * 80;
                #pragma unroll
                for (int q = 0; q < 4; ++q) {
                    f32x4 v = *(const f32x4*)(axp + q * 16);
                    accS[q * 4 + 0] += v[0]; accS[q * 4 + 1] += v[1];
                    accS[q * 4 + 2] += v[2]; accS[q * 4 + 3] += v[3];
                }
                #pragma unroll
                for (int r = 0; r < 16; ++r) {
                    int row = (r & 3) + ((r >> 2) << 3) + (g << 2) + (w << 5);
                    st_coh_h(xpnxt + (size_t)row * IM_ + j0 + col, fast_tanh(accS[r] + bir));
                }
            }
            WAITV(0);
            BARRIER;
            if (tid == 0) arrive_all(bar, blk, t);
        }
    } else {
        // ================= acts/gate/output blocks: cols o0..o0+31 =================
        const int a = blk - NREC;
        const int m = a >> 2;
        const int o0 = a * 32;
        {   // stage W1 = [W_in | W_h] rows o0..o0+31
            const int j = tid >> 3;
            const float* ra = W_in + (size_t)(o0 + j) * I_;
            const float* rb = W_h + (size_t)(o0 + j) * O_ - 256;
            for (int u = (tid & 7); u < 160; u += 8) {
                int k0 = u * 8;
                const float* s = (k0 < 256) ? (ra + k0) : (rb + k0);
                f32x4 lo = *(const f32x4*)s;
                f32x4 hi = *(const f32x4*)(s + 4);
                f16x8 v;
                #pragma unroll
                for (int e = 0; e < 4; ++e) { v[e] = (f16)lo[e]; v[e + 4] = (f16)hi[e]; }
                *(f16x8*)(smem + j * 2560 + ((u ^ (j & 15)) << 4)) = v;
            }
        }
        const float bin = b_in[o0 + col];
        const float per = periods[m], shf = shifts[m];
        LGKM0; BARRIER;

        int addrB[8];
        const int c0 = pair * 5;
        #pragma unroll
        for (int kb = 0; kb < 8; ++kb)
            addrB[kb] = col * 2560 + ((((kb << 1) + g) ^ (col & 15)) << 4) + c0 * 256;

        char* xp_raw = smem + 81920;
        float* lse_lds = (float*)(smem + 124928);
        float* part_lds = (float*)(smem + 125952);
        float* gate_lds = (float*)(smem + 126976);

        const char* xrow0 = (const char*)(ws + OFF_X16) + (size_t)arow * 512 + g * 16;
        const f16* xpB = (const f16*)(ws + OFF_XP3);
        f16* h2 = (f16*)(ws + OFF_H2);
        const int t5 = tid >> 5, cg = tid & 31;
        float hreg[16];
        #pragma unroll
        for (int r = 0; r < 16; ++r) hreg[r] = 0.f;

        for (int t = 0; t < T_; ++t) {
            if (tid == 0) {
                while ((int)ld_rlx(myrepl) < t) __builtin_amdgcn_s_sleep(2);
            }
            BARRIER;
            const int bi = t % 3;
            const f16* xpcur = xpB + (size_t)bi * B_ * IM_;
            const f16* hcur = h2 + (size_t)(t & 1) * B_ * O_;
            f16* hnxt = h2 + (size_t)((t + 1) & 1) * B_ * O_;

            // issue softmax-slice staging loads first (latency hidden under GEMM)
            f16x8 sreg[8];
            {
                const char* sb = (const char*)xpcur + (size_t)m * 512 + (size_t)cg * 16 + (size_t)t5 * 4096;
                ISSUE_STG8(sb, sb + 32768, sb + 2 * 32768, sb + 3 * 32768,
                           sb + 4 * 32768, sb + 5 * 32768, sb + 6 * 32768, sb + 7 * 32768);
            }

            const char* sprow = (const char*)hcur + (size_t)arow * 2048 + g * 16 - 512;
            const char* xrow = xrow0 + (size_t)t * 32768;
            f16x8 abuf[3][8];
            f32x16 acc0, acc1;
            #pragma unroll
            for (int r = 0; r < 16; ++r) { acc0[r] = 0.f; acc1[r] = 0.f; }

            GM_PRO(0); GM_PRO(1); GM_PRO(2);
            // it0: wait sreg + c0; park sreg; compute c0; issue c3
            WAITV(16);
            {
                const int gsw = (cg ^ t5) << 4;
                #pragma unroll
                for (int k = 0; k < 8; ++k)
                    *(f16x8*)(xp_raw + (size_t)(t5 + (k << 3)) * 512 + gsw) = sreg[k];
            }
            #pragma unroll
            for (int kb = 0; kb < 8; ++kb) {
                f16x8 bf = *(const f16x8*)(smem + addrB[kb]);
                if (kb & 1) acc1 = __builtin_amdgcn_mfma_f32_32x32x16_f16(abuf[0][kb], bf, acc1, 0, 0, 0);
                else        acc0 = __builtin_amdgcn_mfma_f32_32x32x16_f16(abuf[0][kb], bf, acc0, 0, 0, 0);
            }
            SCHEDB;
            { const char* p_ = sprow + (c0 + 3) * 256; ISSUE_AS(0, p_); }
            GM_ITA(1, 16, 1); GM_ITA(2, 16, 0); GM_ITA(3, 8, 0); GM_ITA(4, 0, 0);

            f32x16 accS;
            #pragma unroll
            for (int r = 0; r < 16; ++r) accS[r] = acc0[r] + acc1[r];
            if (w >= 2) {
                char* axp = smem + 114688 + (w - 2) * 5120 + lane * 80;
                #pragma unroll
                for (int q = 0; q < 4; ++q) {
                    f32x4 v = { accS[q * 4 + 0], accS[q * 4 + 1], accS[q * 4 + 2], accS[q * 4 + 3] };
                    *(f32x4*)(axp + q * 16) = v;
                }
            }
            LGKM0; BARRIER;
            {   // lse over batch axis, feature i = tid
                // single pass: xp = tanh(..) in [-1,1] => exp in [0.37, 2.72], no overflow
                int i = tid;
                int gq = i >> 3, r2 = (i & 7) * 2;
                float s = 0.f;
                #pragma unroll 8
                for (int b = 0; b < B_; ++b)
                    s += __expf((float)*(const f16*)(xp_raw + b * 512 + ((gq ^ (b & 7)) << 4) + r2));
                lse_lds[i] = __logf(s);
            }
            LGKM0; BARRIER;
            {   // mean surprisal partial dots: thread = (b, quarter)
                int b = tid >> 2, q = tid & 3;
                const float* xr = x + ((size_t)b * T_ + t) * I_ + q * 64;
                float s = 0.f;
                #pragma unroll
                for (int k = 0; k < 8; ++k) {
                    f16x8 xp8 = *(const f16x8*)(xp_raw + (size_t)b * 512 + ((((q << 3) + k) ^ (b & 7)) << 4));
                    f32x4 xa = *(const f32x4*)(xr + k * 8);
                    f32x4 xb2 = *(const f32x4*)(xr + k * 8 + 4);
                    #pragma unroll
                    for (int jj = 0; jj < 4; ++jj)
                        s += ((float)xp8[jj] - lse_lds[(q << 6) + (k << 3) + jj]) * xa[jj];
                    #pragma unroll
                    for (int jj = 0; jj < 4; ++jj)
                        s += ((float)xp8[jj + 4] - lse_lds[(q << 6) + (k << 3) + 4 + jj]) * xb2[jj];
                }
                part_lds[tid] = s;
            }
            LGKM0; BARRIER;
            if (tid < B_) {
                float s = part_lds[tid * 4] + part_lds[tid * 4 + 1] + part_lds[tid * 4 + 2] + part_lds[tid * 4 + 3];
                float mp = (s * (1.f / 256.f)) * per;
                gate_lds[tid] = 0.5f * (sinf((float)t * mp + shf) + 1.f);
                if ((a & 3) == 0) ps[((size_t)tid * T_ + t) * M_ + m] = mp;
            }
            LGKM0; BARRIER;
            if (w < 2) {
                const char* axp = smem + 114688 + w * 5120 + lane * 80;
                #pragma unroll
                for (int q = 0; q < 4; ++q) {
                    f32x4 v = *(const f32x4*)(axp + q * 16);
                    accS[q * 4 + 0] += v[0]; accS[q * 4 + 1] += v[1];
                    accS[q * 4 + 2] += v[2]; accS[q * 4 + 3] += v[3];
                }
                #pragma unroll
                for (int r = 0; r < 16; ++r) {
                    int row = (r & 3) + ((r >> 2) << 3) + (g << 2) + (w << 5);
                    float gt = gate_lds[row];
                    float av = fast_tanh(accS[r] + bin);
                    float y = (1.f - gt) * av + gt * hreg[r];
                    hreg[r] = y;
                    st_coh_h(hnxt + (size_t)row * O_ + o0 + col, y);
                    ys[((size_t)row * T_ + t) * O_ + o0 + col] = y;
                    if (t == T_ - 1) hfin[(size_t)row * O_ + o0 + col] = y;
                }
            }
            WAITV(0);
            BARRIER;
            if (tid == 0) arrive_all(bar, blk, t);
        }
    }
}

extern "C" void kernel_launch(void* const* d_in, const int* in_sizes, int n_in,
                              void* d_out, int out_size, void* d_ws, size_t ws_size,
                              hipStream_t stream) {
    const float* x    = (const float*)d_in[0];
    const float* W_in = (const float*)d_in[1];
    const float* b_in = (const float*)d_in[2];
    const float* W_h  = (const float*)d_in[3];
    const float* W_ir = (const float*)d_in[4];
    const float* b_ir = (const float*)d_in[5];
    const float* W_hr = (const float*)d_in[6];
    const float* per  = (const float*)d_in[7];
    const float* shf  = (const float*)d_in[8];

    hipLaunchKernelGGL(init_kernel, dim3(256), dim3(THREADS), 0, stream,
                       x, (char*)d_ws);
    hipLaunchKernelGGL(cwrnn_kernel, dim3(NB), dim3(THREADS), 0, stream,
                       x, W_in, b_in, W_h, W_ir, b_ir, W_hr, per, shf,
                       (float*)d_out, (char*)d_ws);
}